// Round 4
// baseline (464.685 us; speedup 1.0000x reference)
//
#include <hip/hip_runtime.h>

#define NB 65536

typedef __attribute__((ext_vector_type(8))) short bf16x8;
typedef __attribute__((ext_vector_type(4))) float f32x4;

__device__ __forceinline__ unsigned cvtpk(float lo, float hi) {
  unsigned r;
  asm("v_cvt_pk_bf16_f32 %0, %1, %2" : "=v"(r) : "v"(lo), "v"(hi));
  return r;
}
// safe round-to-nearest-even f32->bf16 (no asm; used on MFMA accumulators)
__device__ __forceinline__ unsigned short f2bf(float f) {
  union { float f; unsigned u; } v; v.f = f;
  return (unsigned short)((v.u + 0x7FFFu + ((v.u >> 16) & 1u)) >> 16);
}
// tanh(x) = sign(x) * (1 - e) / (1 + e),  e = 2^(-2|x|*log2(e)); builtins only
__device__ __forceinline__ float fast_tanh(float x) {
  float e = __builtin_amdgcn_exp2f(__builtin_fabsf(x) * -2.885390081777927f);
  float t = (1.0f - e) * __builtin_amdgcn_rcpf(1.0f + e);
  return __builtin_copysignf(t, x);
}

// ws layout (bf16 element offsets)
#define OFF_A1 0
#define OFF_B1 65536
#define OFF_C1 98304
#define OFF_D1 163840
#define OFF_A2 196608
#define OFF_B2 262144
#define OFF_C2 327680
#define OFF_D2 360448
#define OFF_W1 393216
#define OFF_W2 655360
#define W_TOTAL 917504

struct WPtrs { const float* p[10]; };

__global__ void convert_weights(WPtrs wp, unsigned short* __restrict__ dst) {
  const int off[11] = {OFF_A1, OFF_B1, OFF_C1, OFF_D1, OFF_A2, OFF_B2,
                       OFF_C2, OFF_D2, OFF_W1, OFF_W2, W_TOTAL};
  int gid4 = (blockIdx.x * blockDim.x + threadIdx.x) * 4;
  if (gid4 >= W_TOTAL) return;
  int seg = 0;
  #pragma unroll
  for (int i = 1; i < 10; ++i) seg += (gid4 >= off[i]) ? 1 : 0;
  const float4 f = *(const float4*)(wp.p[seg] + (gid4 - off[seg]));
  uint2 h;
  h.x = cvtpk(f.x, f.y);
  h.y = cvtpk(f.z, f.w);
  *(uint2*)(dst + gid4) = h;
}

#define MFMA16(acc, a, b) \
  acc = __builtin_amdgcn_mfma_f32_16x16x32_bf16(a, b, acc, 0, 0, 0)

// 64-row block tile. LDS strides (bf16 elems), +8 pad keeps 16B alignment.
#define CLD 72    // chunk  [64][72]  ->  9216 B  (x2: double buffer)
#define VLD 264   // vbuf   [64][264] -> 33792 B  (v, then w)
#define HLD 136   // hbuf   [64][136] -> 17408 B  (x2: ping-pong)
#define CH_B 9216
#define VB_B 33792
#define HB_B 17408
#define SMEM_BYTES (2*CH_B + VB_B + 2*HB_B)   // 87040 B

// 16 waves, hard 128-reg cap (1024 thr): per-thread acc max = 32 floats.
__global__ __launch_bounds__(1024, 4) void wh_fused(
    const float* __restrict__ s1, const float* __restrict__ s2,
    const float* __restrict__ u, const unsigned short* __restrict__ wbf,
    const float* __restrict__ b1, const float* __restrict__ b2,
    float* __restrict__ out)
{
  extern __shared__ char smem[];
  unsigned short* cb[2];
  cb[0] = (unsigned short*)smem;
  cb[1] = (unsigned short*)(smem + CH_B);
  unsigned short* vbuf = (unsigned short*)(smem + 2*CH_B);
  unsigned short* hb[2];
  hb[0] = (unsigned short*)(smem + 2*CH_B + VB_B);
  hb[1] = (unsigned short*)(smem + 2*CH_B + VB_B + HB_B);

  const int t   = threadIdx.x;
  const int wid = t >> 6;     // 0..15
  const int mh  = wid >> 3;   // row half (32 rows)
  const int wc  = wid & 7;    // column group
  const int lid = t & 63;
  const int lr  = lid & 15;
  const int lg  = lid >> 4;
  const int row0 = blockIdx.x * 64;
  const int rb  = mh * 32;    // wave's local row base

  // stage a [64 x 64] fp32 panel -> bf16 LDS buffer (1024 threads, 1 ld each)
  auto stage = [&](unsigned short* dst, const float* __restrict__ src,
                   int sld, int c0) {
    const int cg = t & 15;        // 4-float col group
    const int r0 = t >> 4;        // 0..63
    const float4 f = *(const float4*)(src + (size_t)(row0 + r0) * sld + c0 + cg * 4);
    uint2 h;
    h.x = cvtpk(f.x, f.y);
    h.y = cvtpk(f.z, f.w);
    *(uint2*)(dst + r0 * CLD + cg * 4) = h;
  };

  // A fragment from LDS: X[rb + m*16+lr][kk + lg*8 .. +7]
  auto ldsA = [&](const unsigned short* buf, int ld, int m, int kk) -> bf16x8 {
    return *(const bf16x8*)(buf + (rb + m * 16 + lr) * ld + kk + lg * 8);
  };
  // B fragment from global row-major W: W[nrow+lr][kk + lg*8 .. +7]
  auto ldgB = [&](const unsigned short* w, int ld, int nrow, int kk) -> bf16x8 {
    return *(const bf16x8*)(w + (size_t)(nrow + lr) * ld + kk + lg * 8);
  };

  // ================= Phase A: ns1 = [s1|u]@[A1|B1]^T, v = [s1|u]@[C1|D1]^T
  f32x4 ns1[2][2] = {};
  f32x4 vac[2][2] = {};
  stage(cb[0], s1, 256, 0);
  __syncthreads();
  for (int c = 0; c < 6; ++c) {
    if (c < 5) {   // prefetch next chunk into other buffer (overlaps compute)
      if (c + 1 < 4) stage(cb[(c + 1) & 1], s1, 256, (c + 1) * 64);
      else           stage(cb[(c + 1) & 1], u, 128, (c + 1 - 4) * 64);
    }
    const unsigned short* WA = wbf + (c < 4 ? OFF_A1 : OFF_B1);
    const unsigned short* WC = wbf + (c < 4 ? OFF_C1 : OFF_D1);
    const int wld   = (c < 4) ? 256 : 128;
    const int kbase = (c < 4) ? c * 64 : (c - 4) * 64;
    const unsigned short* cbuf = cb[c & 1];
    #pragma unroll
    for (int k2 = 0; k2 < 2; ++k2) {
      bf16x8 a[2];
      #pragma unroll
      for (int m = 0; m < 2; ++m) a[m] = ldsA(cbuf, CLD, m, k2 * 32);
      #pragma unroll
      for (int n = 0; n < 2; ++n) {
        bf16x8 ba = ldgB(WA, wld, wc * 32 + n * 16, kbase + k2 * 32);
        bf16x8 bc = ldgB(WC, wld, wc * 32 + n * 16, kbase + k2 * 32);
        #pragma unroll
        for (int m = 0; m < 2; ++m) {
          MFMA16(ns1[m][n], a[m], ba);
          MFMA16(vac[m][n], a[m], bc);
        }
      }
    }
    __syncthreads();
  }
  // store ns1 (output 0), write v -> vbuf (bf16)
  #pragma unroll
  for (int m = 0; m < 2; ++m)
    #pragma unroll
    for (int n = 0; n < 2; ++n)
      #pragma unroll
      for (int i = 0; i < 4; ++i)
        out[(size_t)(row0 + rb + m * 16 + lg * 4 + i) * 256 + wc * 32 + n * 16 + lr] = ns1[m][n][i];
  #pragma unroll
  for (int m = 0; m < 2; ++m)
    #pragma unroll
    for (int n = 0; n < 2; ++n)
      #pragma unroll
      for (int i = 0; i < 4; ++i)
        vbuf[(rb + m * 16 + lg * 4 + i) * VLD + wc * 32 + n * 16 + lr] = f2bf(vac[m][n][i]);
  __syncthreads();

  // ================= Phase B: w = tanh(v@W1^T + b1) @ W2^T + b2
  f32x4 wac[2][2] = {};
  for (int hc = 0; hc < 8; ++hc) {
    f32x4 hac[2] = {};
    #pragma unroll
    for (int k = 0; k < 8; ++k) {
      bf16x8 a[2];
      #pragma unroll
      for (int m = 0; m < 2; ++m) a[m] = ldsA(vbuf, VLD, m, k * 32);
      bf16x8 bw = ldgB(wbf + OFF_W1, 256, hc * 128 + wc * 16, k * 32);
      #pragma unroll
      for (int m = 0; m < 2; ++m) MFMA16(hac[m], a[m], bw);
    }
    const float bias1 = b1[hc * 128 + wc * 16 + lr];
    unsigned short* hbuf = hb[hc & 1];   // ping-pong: 1 barrier per hc
    #pragma unroll
    for (int m = 0; m < 2; ++m)
      #pragma unroll
      for (int i = 0; i < 4; ++i)
        hbuf[(rb + m * 16 + lg * 4 + i) * HLD + wc * 16 + lr] = f2bf(fast_tanh(hac[m][i] + bias1));
    __syncthreads();   // hbuf[hc&1] writes visible; prev buffer free
    #pragma unroll
    for (int k = 0; k < 4; ++k) {
      bf16x8 a[2];
      #pragma unroll
      for (int m = 0; m < 2; ++m) a[m] = ldsA(hbuf, HLD, m, k * 32);
      #pragma unroll
      for (int n = 0; n < 2; ++n) {
        bf16x8 b2f = ldgB(wbf + OFF_W2, 1024, wc * 32 + n * 16, hc * 128 + k * 32);
        #pragma unroll
        for (int m = 0; m < 2; ++m) MFMA16(wac[m][n], a[m], b2f);
      }
    }
  }
  // w (+b2) -> vbuf; safe: all vbuf reads were pre-BARRIER_7, all waves past it
  #pragma unroll
  for (int m = 0; m < 2; ++m)
    #pragma unroll
    for (int n = 0; n < 2; ++n) {
      const float bias2 = b2[wc * 32 + n * 16 + lr];
      #pragma unroll
      for (int i = 0; i < 4; ++i)
        vbuf[(rb + m * 16 + lg * 4 + i) * VLD + wc * 32 + n * 16 + lr] = f2bf(wac[m][n][i] + bias2);
    }
  stage(cb[0], s2, 256, 0);
  __syncthreads();   // covers vbuf w-writes + stage(0)

  // ================= Phase C: ns2 = s2@A2^T + w@B2^T ; y = s2@C2^T + w@D2^T
  f32x4 ns2[2][2] = {};
  f32x4 yac[2] = {};
  for (int c = 0; c < 4; ++c) {
    if (c < 3) stage(cb[(c + 1) & 1], s2, 256, (c + 1) * 64);
    const unsigned short* cbuf = cb[c & 1];
    #pragma unroll
    for (int k2 = 0; k2 < 2; ++k2) {
      bf16x8 a[2];
      #pragma unroll
      for (int m = 0; m < 2; ++m) a[m] = ldsA(cbuf, CLD, m, k2 * 32);
      const int kk = c * 64 + k2 * 32;
      bf16x8 by = ldgB(wbf + OFF_C2, 256, wc * 16, kk);
      #pragma unroll
      for (int n = 0; n < 2; ++n) {
        bf16x8 ba = ldgB(wbf + OFF_A2, 256, wc * 32 + n * 16, kk);
        #pragma unroll
        for (int m = 0; m < 2; ++m) MFMA16(ns2[m][n], a[m], ba);
      }
      #pragma unroll
      for (int m = 0; m < 2; ++m) MFMA16(yac[m], a[m], by);
    }
    __syncthreads();
  }
  #pragma unroll
  for (int k = 0; k < 8; ++k) {   // w part (A from vbuf, stable now)
    bf16x8 a[2];
    #pragma unroll
    for (int m = 0; m < 2; ++m) a[m] = ldsA(vbuf, VLD, m, k * 32);
    bf16x8 by = ldgB(wbf + OFF_D2, 256, wc * 16, k * 32);
    #pragma unroll
    for (int n = 0; n < 2; ++n) {
      bf16x8 bb = ldgB(wbf + OFF_B2, 256, wc * 32 + n * 16, k * 32);
      #pragma unroll
      for (int m = 0; m < 2; ++m) MFMA16(ns2[m][n], a[m], bb);
    }
    #pragma unroll
    for (int m = 0; m < 2; ++m) MFMA16(yac[m], a[m], by);
  }
  float* out2 = out + (size_t)NB * 256;
  float* outy = out + (size_t)NB * 512;
  #pragma unroll
  for (int m = 0; m < 2; ++m)
    #pragma unroll
    for (int n = 0; n < 2; ++n)
      #pragma unroll
      for (int i = 0; i < 4; ++i)
        out2[(size_t)(row0 + rb + m * 16 + lg * 4 + i) * 256 + wc * 32 + n * 16 + lr] = ns2[m][n][i];
  #pragma unroll
  for (int m = 0; m < 2; ++m)
    #pragma unroll
    for (int i = 0; i < 4; ++i)
      outy[(size_t)(row0 + rb + m * 16 + lg * 4 + i) * 128 + wc * 16 + lr] = yac[m][i];
}

extern "C" void kernel_launch(void* const* d_in, const int* in_sizes, int n_in,
                              void* d_out, int out_size, void* d_ws, size_t ws_size,
                              hipStream_t stream) {
  const float* s1 = (const float*)d_in[0];
  const float* s2 = (const float*)d_in[1];
  const float* u  = (const float*)d_in[2];
  WPtrs wp;
  wp.p[0] = (const float*)d_in[3];   // A1
  wp.p[1] = (const float*)d_in[4];   // B1
  wp.p[2] = (const float*)d_in[5];   // C1
  wp.p[3] = (const float*)d_in[6];   // D1
  wp.p[4] = (const float*)d_in[7];   // A2
  wp.p[5] = (const float*)d_in[8];   // B2
  wp.p[6] = (const float*)d_in[9];   // C2
  wp.p[7] = (const float*)d_in[10];  // D2
  wp.p[8] = (const float*)d_in[11];  // W1
  wp.p[9] = (const float*)d_in[13];  // W2
  const float* b1 = (const float*)d_in[12];
  const float* b2 = (const float*)d_in[14];
  unsigned short* wbf = (unsigned short*)d_ws;

  convert_weights<<<dim3((W_TOTAL / 4 + 511) / 512), dim3(512), 0, stream>>>(wp, wbf);
  wh_fused<<<dim3(NB / 64), dim3(1024), SMEM_BYTES, stream>>>(
      s1, s2, u, wbf, b1, b2, (float*)d_out);
}

// Round 5
// 411.949 us; speedup vs baseline: 1.1280x; 1.1280x over previous
//
#include <hip/hip_runtime.h>

#define NB 65536

typedef __attribute__((ext_vector_type(8))) short bf16x8;
typedef __attribute__((ext_vector_type(4))) float f32x4;

__device__ __forceinline__ unsigned cvtpk(float lo, float hi) {
  unsigned r;
  asm("v_cvt_pk_bf16_f32 %0, %1, %2" : "=v"(r) : "v"(lo), "v"(hi));
  return r;
}
// safe round-to-nearest-even f32->bf16 (no asm; used on MFMA accumulators)
__device__ __forceinline__ unsigned short f2bf(float f) {
  union { float f; unsigned u; } v; v.f = f;
  return (unsigned short)((v.u + 0x7FFFu + ((v.u >> 16) & 1u)) >> 16);
}
// tanh(x) = sign(x) * (1 - e) / (1 + e),  e = 2^(-2|x|*log2(e)); builtins only
__device__ __forceinline__ float fast_tanh(float x) {
  float e = __builtin_amdgcn_exp2f(__builtin_fabsf(x) * -2.885390081777927f);
  float t = (1.0f - e) * __builtin_amdgcn_rcpf(1.0f + e);
  return __builtin_copysignf(t, x);
}

// ws layout (bf16 element offsets)
#define OFF_A1 0
#define OFF_B1 65536
#define OFF_C1 98304
#define OFF_D1 163840
#define OFF_A2 196608
#define OFF_B2 262144
#define OFF_C2 327680
#define OFF_D2 360448
#define OFF_W1 393216
#define OFF_W2 655360
#define W_TOTAL 917504

struct WPtrs { const float* p[10]; };

__global__ void convert_weights(WPtrs wp, unsigned short* __restrict__ dst) {
  const int off[11] = {OFF_A1, OFF_B1, OFF_C1, OFF_D1, OFF_A2, OFF_B2,
                       OFF_C2, OFF_D2, OFF_W1, OFF_W2, W_TOTAL};
  int gid4 = (blockIdx.x * blockDim.x + threadIdx.x) * 4;
  if (gid4 >= W_TOTAL) return;
  int seg = 0;
  #pragma unroll
  for (int i = 1; i < 10; ++i) seg += (gid4 >= off[i]) ? 1 : 0;
  const float4 f = *(const float4*)(wp.p[seg] + (gid4 - off[seg]));
  uint2 h;
  h.x = cvtpk(f.x, f.y);
  h.y = cvtpk(f.z, f.w);
  *(uint2*)(dst + gid4) = h;
}

#define MFMA16(acc, a, b) \
  acc = __builtin_amdgcn_mfma_f32_16x16x32_bf16(a, b, acc, 0, 0, 0)

// LDS geometry (bf16 elems). Strides keep 16B row alignment and dword-stride
// === 4 mod 32 -> 2-way bank aliasing on 16-row ds_read_b128 groups (free).
#define CLD 72    // chunk [128][72]   -> 18432 B each (x2 dbuf)
#define VLD 264   // vbuf  [128][264]  -> 67584 B (v, later w)
#define HLD 136   // hbuf  [128][136]  -> 34816 B each (x2 ping-pong)
// layout: [vbuf 67584][region2 69632 = hbuf0|hbuf1, aliased by cb0|cb1]
#define SMEM_BYTES (67584 + 2*34816)   // 137216

// 8 waves, 128-row tile. Wave = m8 x n-wide column strip.
__global__ __launch_bounds__(512, 2) void wh_fused(
    const float* __restrict__ s1, const float* __restrict__ s2,
    const float* __restrict__ u, const unsigned short* __restrict__ wbf,
    const float* __restrict__ b1, const float* __restrict__ b2,
    float* __restrict__ out)
{
  extern __shared__ char smem[];
  unsigned short* vbuf = (unsigned short*)smem;
  unsigned short* hbp[2];
  hbp[0] = (unsigned short*)(smem + 67584);
  hbp[1] = (unsigned short*)(smem + 67584 + 34816);
  unsigned short* cbp[2];
  cbp[0] = (unsigned short*)(smem + 67584);           // aliases hbuf0
  cbp[1] = (unsigned short*)(smem + 67584 + 18432);   // aliases hbuf0/1 tail

  const int t   = threadIdx.x;
  const int wc  = t >> 6;     // wave 0..7
  const int lid = t & 63;
  const int lr  = lid & 15;
  const int lg  = lid >> 4;
  const int row0 = blockIdx.x * 128;

  // --- T14 split staging of a [128 x 64] fp32 panel ---
  float4 st[4];
  auto stageLoad = [&](const float* __restrict__ src, int sld, int c0) {
    const int cg = t & 15, r0 = t >> 4;   // r0 0..31
    #pragma unroll
    for (int rr = 0; rr < 4; ++rr)
      st[rr] = *(const float4*)(src + (size_t)(row0 + r0 + rr * 32) * sld + c0 + cg * 4);
  };
  auto stageWrite = [&](unsigned short* dst) {
    const int cg = t & 15, r0 = t >> 4;
    #pragma unroll
    for (int rr = 0; rr < 4; ++rr) {
      uint2 h;
      h.x = cvtpk(st[rr].x, st[rr].y);
      h.y = cvtpk(st[rr].z, st[rr].w);
      *(uint2*)(dst + (r0 + rr * 32) * CLD + cg * 4) = h;
    }
  };
  // A fragment from LDS: X[m*16+lr][kk + lg*8 .. +7]
  auto ldsA = [&](const unsigned short* buf, int ld, int m, int kk) -> bf16x8 {
    return *(const bf16x8*)(buf + (m * 16 + lr) * ld + kk + lg * 8);
  };
  // B fragment from global row-major W: W[nrow+lr][kk + lg*8 .. +7]
  auto ldgB = [&](const unsigned short* w, int ld, int nrow, int kk) -> bf16x8 {
    return *(const bf16x8*)(w + (size_t)(nrow + lr) * ld + kk + lg * 8);
  };

  // ============ Phase A: [ns1|v] = [s1|u] @ [A1|B1 ; C1|D1]^T ============
  // wave wc covers concat-cols wc*64..+63 (wc<4 -> ns1, wc>=4 -> v), m=8, n=4
  f32x4 acc[8][4] = {};
  {
    const unsigned short* Wk1 = wbf + (wc < 4 ? OFF_A1 : OFF_C1);  // K from s1
    const unsigned short* Wk2 = wbf + (wc < 4 ? OFF_B1 : OFF_D1);  // K from u
    const int cb4 = (wc & 3) * 64;
    stageLoad(s1, 256, 0);
    stageWrite(cbp[0]);
    __syncthreads();
    for (int c = 0; c < 6; ++c) {
      if (c < 5) {
        if (c + 1 < 4) stageLoad(s1, 256, (c + 1) * 64);
        else           stageLoad(u, 128, (c + 1 - 4) * 64);
      }
      const unsigned short* W = (c < 4) ? Wk1 : Wk2;
      const int wld = (c < 4) ? 256 : 128;
      const int kb  = (c < 4) ? c * 64 : (c - 4) * 64;
      const unsigned short* cbuf = cbp[c & 1];
      #pragma unroll
      for (int k2 = 0; k2 < 2; ++k2) {
        bf16x8 a[8];
        #pragma unroll
        for (int m = 0; m < 8; ++m) a[m] = ldsA(cbuf, CLD, m, k2 * 32);
        #pragma unroll
        for (int n = 0; n < 4; ++n) {
          bf16x8 b = ldgB(W, wld, cb4 + n * 16, kb + k2 * 32);
          #pragma unroll
          for (int m = 0; m < 8; ++m) MFMA16(acc[m][n], a[m], b);
        }
      }
      if (c < 5) stageWrite(cbp[(c + 1) & 1]);
      __syncthreads();
    }
    // epilogue: ns1 -> out (wc<4); v -> vbuf (wc>=4)
    if (wc < 4) {
      #pragma unroll
      for (int m = 0; m < 8; ++m)
        #pragma unroll
        for (int n = 0; n < 4; ++n)
          #pragma unroll
          for (int i = 0; i < 4; ++i)
            out[(size_t)(row0 + m * 16 + lg * 4 + i) * 256 + wc * 64 + n * 16 + lr] = acc[m][n][i];
    } else {
      #pragma unroll
      for (int m = 0; m < 8; ++m)
        #pragma unroll
        for (int n = 0; n < 4; ++n)
          #pragma unroll
          for (int i = 0; i < 4; ++i)
            vbuf[(m * 16 + lg * 4 + i) * VLD + (wc - 4) * 64 + n * 16 + lr] = f2bf(acc[m][n][i]);
    }
    __syncthreads();
  }

  // ===== Phase B: producers (wc>=4) h-chunks; consumers (wc<4) w accum =====
  // 8 hidden chunks of 128; hbuf ping-pong; both k-loops overlap per stage.
  f32x4 wac[8][4] = {};
  {
    const int pq = wc & 3;
    for (int s = 0; s < 9; ++s) {
      if (wc >= 4 && s < 8) {          // produce h[s] -> hbuf[s&1]
        f32x4 hac[8][2] = {};
        #pragma unroll
        for (int k = 0; k < 8; ++k) {
          bf16x8 a[8];
          #pragma unroll
          for (int m = 0; m < 8; ++m) a[m] = ldsA(vbuf, VLD, m, k * 32);
          #pragma unroll
          for (int n = 0; n < 2; ++n) {
            bf16x8 b = ldgB(wbf + OFF_W1, 256, s * 128 + pq * 32 + n * 16, k * 32);
            #pragma unroll
            for (int m = 0; m < 8; ++m) MFMA16(hac[m][n], a[m], b);
          }
        }
        unsigned short* hb = hbp[s & 1];
        #pragma unroll
        for (int n = 0; n < 2; ++n) {
          const float b1v = b1[s * 128 + pq * 32 + n * 16 + lr];
          #pragma unroll
          for (int m = 0; m < 8; ++m)
            #pragma unroll
            for (int i = 0; i < 4; ++i)
              hb[(m * 16 + lg * 4 + i) * HLD + pq * 32 + n * 16 + lr] =
                  f2bf(fast_tanh(hac[m][n][i] + b1v));
        }
      }
      if (wc < 4 && s >= 1) {          // consume h[s-1] from hbuf[(s-1)&1]
        const unsigned short* hb = hbp[(s - 1) & 1];
        #pragma unroll
        for (int k = 0; k < 4; ++k) {
          bf16x8 a[8];
          #pragma unroll
          for (int m = 0; m < 8; ++m) a[m] = ldsA(hb, HLD, m, k * 32);
          #pragma unroll
          for (int n = 0; n < 4; ++n) {
            bf16x8 b = ldgB(wbf + OFF_W2, 1024, wc * 64 + n * 16, (s - 1) * 128 + k * 32);
            #pragma unroll
            for (int m = 0; m < 8; ++m) MFMA16(wac[m][n], a[m], b);
          }
        }
      }
      __syncthreads();
    }
    // consumers write w (+b2) -> vbuf (v no longer needed)
    if (wc < 4) {
      #pragma unroll
      for (int n = 0; n < 4; ++n) {
        const float b2v = b2[wc * 64 + n * 16 + lr];
        #pragma unroll
        for (int m = 0; m < 8; ++m)
          #pragma unroll
          for (int i = 0; i < 4; ++i)
            vbuf[(m * 16 + lg * 4 + i) * VLD + wc * 64 + n * 16 + lr] =
                f2bf(wac[m][n][i] + b2v);
      }
    }
    __syncthreads();
  }

  // ====== Phase C: [ns2|y] = s2 @ [A2;C2]^T + w @ [B2;D2]^T  (n=3) ======
  f32x4 cac[8][3] = {};
  {
    stageLoad(s2, 256, 0);
    stageWrite(cbp[0]);
    __syncthreads();
    for (int c = 0; c < 4; ++c) {
      if (c < 3) stageLoad(s2, 256, (c + 1) * 64);
      const unsigned short* cbuf = cbp[c & 1];
      #pragma unroll
      for (int k2 = 0; k2 < 2; ++k2) {
        bf16x8 a[8];
        #pragma unroll
        for (int m = 0; m < 8; ++m) a[m] = ldsA(cbuf, CLD, m, k2 * 32);
        const int kk = c * 64 + k2 * 32;
        #pragma unroll
        for (int n = 0; n < 3; ++n) {
          const int cg = wc * 48 + n * 16;
          const unsigned short* W = (cg < 256)
              ? (wbf + OFF_A2 + (size_t)cg * 256)
              : (wbf + OFF_C2 + (size_t)(cg - 256) * 256);
          bf16x8 b = *(const bf16x8*)(W + (size_t)lr * 256 + kk + lg * 8);
          #pragma unroll
          for (int m = 0; m < 8; ++m) MFMA16(cac[m][n], a[m], b);
        }
      }
      if (c < 3) stageWrite(cbp[(c + 1) & 1]);
      __syncthreads();
    }
    #pragma unroll
    for (int k = 0; k < 8; ++k) {      // w-part: A from vbuf
      bf16x8 a[8];
      #pragma unroll
      for (int m = 0; m < 8; ++m) a[m] = ldsA(vbuf, VLD, m, k * 32);
      #pragma unroll
      for (int n = 0; n < 3; ++n) {
        const int cg = wc * 48 + n * 16;
        const unsigned short* W = (cg < 256)
            ? (wbf + OFF_B2 + (size_t)cg * 256)
            : (wbf + OFF_D2 + (size_t)(cg - 256) * 256);
        bf16x8 b = *(const bf16x8*)(W + (size_t)lr * 256 + k * 32 + lg * 8);
        #pragma unroll
        for (int m = 0; m < 8; ++m) MFMA16(cac[m][n], a[m], b);
      }
    }
    float* out2 = out + (size_t)NB * 256;
    float* outy = out + (size_t)NB * 512;
    #pragma unroll
    for (int n = 0; n < 3; ++n) {
      const int cg = wc * 48 + n * 16;
      #pragma unroll
      for (int m = 0; m < 8; ++m)
        #pragma unroll
        for (int i = 0; i < 4; ++i) {
          const size_t row = row0 + m * 16 + lg * 4 + i;
          if (cg < 256) out2[row * 256 + cg + lr] = cac[m][n][i];
          else          outy[row * 128 + cg - 256 + lr] = cac[m][n][i];
        }
    }
  }
}

extern "C" void kernel_launch(void* const* d_in, const int* in_sizes, int n_in,
                              void* d_out, int out_size, void* d_ws, size_t ws_size,
                              hipStream_t stream) {
  const float* s1 = (const float*)d_in[0];
  const float* s2 = (const float*)d_in[1];
  const float* u  = (const float*)d_in[2];
  WPtrs wp;
  wp.p[0] = (const float*)d_in[3];   // A1
  wp.p[1] = (const float*)d_in[4];   // B1
  wp.p[2] = (const float*)d_in[5];   // C1
  wp.p[3] = (const float*)d_in[6];   // D1
  wp.p[4] = (const float*)d_in[7];   // A2
  wp.p[5] = (const float*)d_in[8];   // B2
  wp.p[6] = (const float*)d_in[9];   // C2
  wp.p[7] = (const float*)d_in[10];  // D2
  wp.p[8] = (const float*)d_in[11];  // W1
  wp.p[9] = (const float*)d_in[13];  // W2
  const float* b1 = (const float*)d_in[12];
  const float* b2 = (const float*)d_in[14];
  unsigned short* wbf = (unsigned short*)d_ws;

  convert_weights<<<dim3((W_TOTAL / 4 + 511) / 512), dim3(512), 0, stream>>>(wp, wbf);
  wh_fused<<<dim3(NB / 128), dim3(512), SMEM_BYTES, stream>>>(
      s1, s2, u, wbf, b1, b2, (float*)d_out);
}

// Round 6
// 343.569 us; speedup vs baseline: 1.3525x; 1.1990x over previous
//
#include <hip/hip_runtime.h>

#define NB 65536

typedef __attribute__((ext_vector_type(8))) short bf16x8;
typedef __attribute__((ext_vector_type(4))) float f32x4;

__device__ __forceinline__ unsigned cvtpk(float lo, float hi) {
  unsigned r;
  asm("v_cvt_pk_bf16_f32 %0, %1, %2" : "=v"(r) : "v"(lo), "v"(hi));
  return r;
}
__device__ __forceinline__ unsigned short f2bf(float f) {
  union { float f; unsigned u; } v; v.f = f;
  return (unsigned short)((v.u + 0x7FFFu + ((v.u >> 16) & 1u)) >> 16);
}
__device__ __forceinline__ float fast_tanh(float x) {
  float e = __builtin_amdgcn_exp2f(__builtin_fabsf(x) * -2.885390081777927f);
  float t = (1.0f - e) * __builtin_amdgcn_rcpf(1.0f + e);
  return __builtin_copysignf(t, x);
}

#define MFMA16(acc, a, b) \
  acc = __builtin_amdgcn_mfma_f32_16x16x32_bf16(a, b, acc, 0, 0, 0)

// ws layout (bf16 element offsets)
#define OFF_W1  0         // W1 bf16 [1024][256]
#define OFF_KAS 262144    // [A1;C1] [512][256]
#define OFF_KAU 393216    // [B1;D1] [512][128]
#define OFF_KBS 458752    // [A2;C2] [384][256]
#define OFF_KBH 557056    // [WB;WD] [384][1024]  (fused B2@W2 ; D2@W2)
#define WS_BF16_END 950272
#define OFF_BIAS_BYTES ((size_t)WS_BF16_END * 2)   // 1900544, 16B aligned

// ===================== prep: convert + weight fusion =====================
struct CvtPtrs { const float* s[7]; };   // A1,C1,B1,D1,A2,C2,W1

__global__ void prep(CvtPtrs cp, const float* __restrict__ B2,
                     const float* __restrict__ D2, const float* __restrict__ W2,
                     const float* __restrict__ b2,
                     unsigned short* __restrict__ wbf, float* __restrict__ bias384) {
  const int bid = blockIdx.x, tid = threadIdx.x;
  if (bid < 544) {                     // plain fp32->bf16 converts
    const int cum[8]  = {0, 65536, 131072, 163840, 196608, 262144, 294912, 557056};
    const int dsto[7] = {OFF_KAS, OFF_KAS + 65536, OFF_KAU, OFF_KAU + 32768,
                         OFF_KBS, OFF_KBS + 65536, OFF_W1};
    const int g4 = (bid * 256 + tid) * 4;
    if (g4 < 557056) {
      int seg = 0;
      #pragma unroll
      for (int i = 1; i < 7; ++i) seg += (g4 >= cum[i]) ? 1 : 0;
      const float4 f = *(const float4*)(cp.s[seg] + (g4 - cum[seg]));
      uint2 h;
      h.x = cvtpk(f.x, f.y);
      h.y = cvtpk(f.z, f.w);
      *(uint2*)(wbf + dsto[seg] + (g4 - cum[seg])) = h;
    }
  } else if (bid < 544 + 192) {        // fused [WB;WD] = [B2;D2] @ W2
    const int fb  = bid - 544;
    const int rb8 = (fb >> 2) * 8;     // never straddles 256
    const int k   = (fb & 3) * 256 + tid;
    float acc[8] = {};
    for (int j = 0; j < 256; ++j) {
      const float w2v = W2[(size_t)j * 1024 + k];
      #pragma unroll
      for (int r = 0; r < 8; ++r) {
        const int row = rb8 + r;
        const float sv = (row < 256) ? B2[row * 256 + j] : D2[(row - 256) * 256 + j];
        acc[r] += sv * w2v;
      }
    }
    #pragma unroll
    for (int r = 0; r < 8; ++r)
      wbf[OFF_KBH + (size_t)(rb8 + r) * 1024 + k] = f2bf(acc[r]);
  } else {                              // bias384 = [B2;D2] @ b2
    const int r = (bid - 736) * 256 + tid;
    if (r < 384) {
      const float* S = (r < 256) ? (B2 + r * 256) : (D2 + (r - 256) * 256);
      float a = 0.f;
      for (int j = 0; j < 256; ++j) a += S[j] * b2[j];
      bias384[r] = a;
    }
  }
}

// ===================== KA: [ns1 | v] = [s1|u] @ Wcatᵀ =====================
#define CLD 72
__global__ __launch_bounds__(512, 4) void ka(
    const float* __restrict__ s1, const float* __restrict__ u,
    const unsigned short* __restrict__ wbf,
    float* __restrict__ ns1, unsigned short* __restrict__ vout)
{
  __shared__ unsigned short cb[2][64 * CLD];   // 18432 B
  const int t = threadIdx.x, wc = t >> 6, lid = t & 63;
  const int lr = lid & 15, lg = lid >> 4;
  const int row0 = blockIdx.x * 64;

  float4 st0, st1;
  auto stageLoad = [&](const float* __restrict__ src, int sld, int c0) {
    const int cg = t & 15, r0 = t >> 4;   // r0 0..31
    st0 = *(const float4*)(src + (size_t)(row0 + r0) * sld + c0 + cg * 4);
    st1 = *(const float4*)(src + (size_t)(row0 + r0 + 32) * sld + c0 + cg * 4);
  };
  auto stageWrite = [&](unsigned short* dst) {
    const int cg = t & 15, r0 = t >> 4;
    uint2 h0, h1;
    h0.x = cvtpk(st0.x, st0.y); h0.y = cvtpk(st0.z, st0.w);
    h1.x = cvtpk(st1.x, st1.y); h1.y = cvtpk(st1.z, st1.w);
    *(uint2*)(dst + r0 * CLD + cg * 4) = h0;
    *(uint2*)(dst + (r0 + 32) * CLD + cg * 4) = h1;
  };

  f32x4 acc[4][4] = {};
  stageLoad(s1, 256, 0);
  stageWrite(cb[0]);
  __syncthreads();
  for (int c = 0; c < 6; ++c) {
    if (c < 5) {
      if (c + 1 < 4) stageLoad(s1, 256, (c + 1) * 64);
      else           stageLoad(u, 128, (c + 1 - 4) * 64);
    }
    const unsigned short* W = wbf + (c < 4 ? OFF_KAS : OFF_KAU);
    const int wld = (c < 4) ? 256 : 128;
    const int kb  = (c < 4) ? c * 64 : (c - 4) * 64;
    const unsigned short* cbuf = cb[c & 1];
    #pragma unroll
    for (int k2 = 0; k2 < 2; ++k2) {
      bf16x8 a[4];
      #pragma unroll
      for (int m = 0; m < 4; ++m)
        a[m] = *(const bf16x8*)(cbuf + (m * 16 + lr) * CLD + k2 * 32 + lg * 8);
      #pragma unroll
      for (int n = 0; n < 4; ++n) {
        bf16x8 b = *(const bf16x8*)(W + (size_t)(wc * 64 + n * 16 + lr) * wld + kb + k2 * 32 + lg * 8);
        #pragma unroll
        for (int m = 0; m < 4; ++m) MFMA16(acc[m][n], a[m], b);
      }
    }
    if (c < 5) stageWrite(cb[(c + 1) & 1]);
    __syncthreads();
  }
  if (wc < 4) {          // ns1 (cols wc*64..)
    #pragma unroll
    for (int m = 0; m < 4; ++m)
      #pragma unroll
      for (int n = 0; n < 4; ++n)
        #pragma unroll
        for (int i = 0; i < 4; ++i)
          ns1[(size_t)(row0 + m * 16 + lg * 4 + i) * 256 + wc * 64 + n * 16 + lr] = acc[m][n][i];
  } else {               // v bf16 (cols (wc-4)*64..)
    #pragma unroll
    for (int m = 0; m < 4; ++m)
      #pragma unroll
      for (int n = 0; n < 4; ++n)
        #pragma unroll
        for (int i = 0; i < 4; ++i)
          vout[(size_t)(row0 + m * 16 + lg * 4 + i) * 256 + (wc - 4) * 64 + n * 16 + lr] = f2bf(acc[m][n][i]);
  }
}

// ============ KB: [ns2|y] = s2@[A2;C2]ᵀ + h@[WB;WD]ᵀ + bias ============
#define VLD 264
#define HLD 136
__global__ __launch_bounds__(512, 4) void kb(
    const float* __restrict__ s2, const unsigned short* __restrict__ vsrc,
    const unsigned short* __restrict__ wbf,
    const float* __restrict__ b1, const float* __restrict__ bias384,
    float* __restrict__ out2, float* __restrict__ outy)
{
  __shared__ unsigned short vb[64 * VLD];        // 33792 B
  __shared__ unsigned short hbl[2][64 * HLD];    // 34816 B (also aliased as s2 chunk bufs)
  unsigned short* cbp0 = &hbl[0][0];
  unsigned short* cbp1 = &hbl[0][0] + 64 * CLD;  // both fit inside hbl; s2-phase only

  const int t = threadIdx.x, wc = t >> 6, lid = t & 63;
  const int lr = lid & 15, lg = lid >> 4;
  const int row0 = blockIdx.x * 64;

  // stage v (bf16 copy) -> vb
  for (int g = t; g < 2048; g += 512) {
    const int row = g >> 5, c8 = (g & 31) * 8;
    *(uint4*)(vb + row * VLD + c8) =
        *(const uint4*)(vsrc + (size_t)(row0 + row) * 256 + c8);
  }

  float4 st0, st1;
  auto stageLoad = [&](const float* __restrict__ src, int sld, int c0) {
    const int cg = t & 15, r0 = t >> 4;
    st0 = *(const float4*)(src + (size_t)(row0 + r0) * sld + c0 + cg * 4);
    st1 = *(const float4*)(src + (size_t)(row0 + r0 + 32) * sld + c0 + cg * 4);
  };
  auto stageWrite = [&](unsigned short* dst) {
    const int cg = t & 15, r0 = t >> 4;
    uint2 h0, h1;
    h0.x = cvtpk(st0.x, st0.y); h0.y = cvtpk(st0.z, st0.w);
    h1.x = cvtpk(st1.x, st1.y); h1.y = cvtpk(st1.z, st1.w);
    *(uint2*)(dst + r0 * CLD + cg * 4) = h0;
    *(uint2*)(dst + (r0 + 32) * CLD + cg * 4) = h1;
  };

  f32x4 acc[4][3] = {};
  // ---- s2 part: acc += s2 @ [A2;C2]ᵀ (4 staged chunks) ----
  stageLoad(s2, 256, 0);
  stageWrite(cbp0);
  __syncthreads();    // also covers vb staging
  for (int c = 0; c < 4; ++c) {
    if (c < 3) stageLoad(s2, 256, (c + 1) * 64);
    const unsigned short* cbuf = (c & 1) ? cbp1 : cbp0;
    #pragma unroll
    for (int k2 = 0; k2 < 2; ++k2) {
      bf16x8 a[4];
      #pragma unroll
      for (int m = 0; m < 4; ++m)
        a[m] = *(const bf16x8*)(cbuf + (m * 16 + lr) * CLD + k2 * 32 + lg * 8);
      #pragma unroll
      for (int n = 0; n < 3; ++n) {
        bf16x8 b = *(const bf16x8*)(wbf + OFF_KBS +
            (size_t)(wc * 48 + n * 16 + lr) * 256 + c * 64 + k2 * 32 + lg * 8);
        #pragma unroll
        for (int m = 0; m < 4; ++m) MFMA16(acc[m][n], a[m], b);
      }
    }
    if (c < 3) stageWrite((c & 1) ? cbp0 : cbp1);
    __syncthreads();
  }

  // ---- h part: 8 chunks of 128 hidden; h=tanh(vb@W1ᵀ+b1); acc += h@[WB;WD]ᵀ ----
  for (int hc = 0; hc < 8; ++hc) {
    f32x4 hac[4] = {};
    #pragma unroll
    for (int k = 0; k < 8; ++k) {
      bf16x8 a[4];
      #pragma unroll
      for (int m = 0; m < 4; ++m)
        a[m] = *(const bf16x8*)(vb + (m * 16 + lr) * VLD + k * 32 + lg * 8);
      bf16x8 bw = *(const bf16x8*)(wbf + OFF_W1 +
          (size_t)(hc * 128 + wc * 16 + lr) * 256 + k * 32 + lg * 8);
      #pragma unroll
      for (int m = 0; m < 4; ++m) MFMA16(hac[m], a[m], bw);
    }
    const float b1v = b1[hc * 128 + wc * 16 + lr];
    unsigned short* hb = hbl[hc & 1];
    #pragma unroll
    for (int m = 0; m < 4; ++m)
      #pragma unroll
      for (int i = 0; i < 4; ++i)
        hb[(m * 16 + lg * 4 + i) * HLD + wc * 16 + lr] = f2bf(fast_tanh(hac[m][i] + b1v));
    __syncthreads();
    #pragma unroll
    for (int kk = 0; kk < 4; ++kk) {
      bf16x8 a[4];
      #pragma unroll
      for (int m = 0; m < 4; ++m)
        a[m] = *(const bf16x8*)(hb + (m * 16 + lr) * HLD + kk * 32 + lg * 8);
      #pragma unroll
      for (int n = 0; n < 3; ++n) {
        bf16x8 b = *(const bf16x8*)(wbf + OFF_KBH +
            (size_t)(wc * 48 + n * 16 + lr) * 1024 + hc * 128 + kk * 32 + lg * 8);
        #pragma unroll
        for (int m = 0; m < 4; ++m) MFMA16(acc[m][n], a[m], b);
      }
    }
  }

  // ---- epilogue: + bias, split ns2 / y ----
  #pragma unroll
  for (int n = 0; n < 3; ++n) {
    const int col = wc * 48 + n * 16 + lr;
    const float bv = bias384[col];
    #pragma unroll
    for (int m = 0; m < 4; ++m)
      #pragma unroll
      for (int i = 0; i < 4; ++i) {
        const size_t row = row0 + m * 16 + lg * 4 + i;
        const float val = acc[m][n][i] + bv;
        if (col < 256) out2[row * 256 + col] = val;
        else           outy[row * 128 + col - 256] = val;
      }
  }
}

extern "C" void kernel_launch(void* const* d_in, const int* in_sizes, int n_in,
                              void* d_out, int out_size, void* d_ws, size_t ws_size,
                              hipStream_t stream) {
  const float* s1 = (const float*)d_in[0];
  const float* s2 = (const float*)d_in[1];
  const float* u  = (const float*)d_in[2];
  CvtPtrs cp;
  cp.s[0] = (const float*)d_in[3];   // A1
  cp.s[1] = (const float*)d_in[5];   // C1
  cp.s[2] = (const float*)d_in[4];   // B1
  cp.s[3] = (const float*)d_in[6];   // D1
  cp.s[4] = (const float*)d_in[7];   // A2
  cp.s[5] = (const float*)d_in[9];   // C2
  cp.s[6] = (const float*)d_in[11];  // W1
  const float* B2 = (const float*)d_in[8];
  const float* D2 = (const float*)d_in[10];
  const float* W2 = (const float*)d_in[13];
  const float* b1 = (const float*)d_in[12];
  const float* b2 = (const float*)d_in[14];

  unsigned short* wbf = (unsigned short*)d_ws;
  float* bias384 = (float*)((char*)d_ws + OFF_BIAS_BYTES);
  float* out = (float*)d_out;
  float* out2 = out + (size_t)NB * 256;
  float* outy = out + (size_t)NB * 512;
  // v (bf16, 32 MB) lives in the y-region (64 MB) until KB overwrites y
  unsigned short* vtmp = (unsigned short*)outy;

  prep<<<dim3(738), dim3(256), 0, stream>>>(cp, B2, D2, W2, b2, wbf, bias384);
  ka<<<dim3(NB / 64), dim3(512), 0, stream>>>(s1, u, wbf, out, vtmp);
  kb<<<dim3(NB / 64), dim3(512), 0, stream>>>(s2, vtmp, wbf, b1, bias384, out2, outy);
}

// Round 7
// 343.366 us; speedup vs baseline: 1.3533x; 1.0006x over previous
//
#include <hip/hip_runtime.h>

#define NB 65536

typedef __attribute__((ext_vector_type(8))) short bf16x8;
typedef __attribute__((ext_vector_type(4))) float f32x4;

__device__ __forceinline__ unsigned cvtpk(float lo, float hi) {
  unsigned r;
  asm("v_cvt_pk_bf16_f32 %0, %1, %2" : "=v"(r) : "v"(lo), "v"(hi));
  return r;
}
__device__ __forceinline__ unsigned short f2bf(float f) {
  union { float f; unsigned u; } v; v.f = f;
  return (unsigned short)((v.u + 0x7FFFu + ((v.u >> 16) & 1u)) >> 16);
}
__device__ __forceinline__ float fast_tanh(float x) {
  float e = __builtin_amdgcn_exp2f(__builtin_fabsf(x) * -2.885390081777927f);
  float t = (1.0f - e) * __builtin_amdgcn_rcpf(1.0f + e);
  return __builtin_copysignf(t, x);
}

#define MFMA16(acc, a, b) \
  acc = __builtin_amdgcn_mfma_f32_16x16x32_bf16(a, b, acc, 0, 0, 0)

// ws layout (bf16 element offsets)
#define OFF_W1  0         // W1 bf16 [1024][256]
#define OFF_KAS 262144    // [A1;C1] [512][256]
#define OFF_KAU 393216    // [B1;D1] [512][128]
#define OFF_KBS 458752    // [A2;C2] [384][256]
#define OFF_KBH 557056    // [WB;WD] [384][1024]  (fused B2@W2 ; D2@W2)
#define WS_BF16_END 950272
#define OFF_BIAS_BYTES ((size_t)WS_BF16_END * 2)   // 16B aligned

// ===================== prep: convert + weight fusion =====================
struct CvtPtrs { const float* s[7]; };   // A1,C1,B1,D1,A2,C2,W1

__global__ void prep(CvtPtrs cp, const float* __restrict__ B2,
                     const float* __restrict__ D2, const float* __restrict__ W2,
                     const float* __restrict__ b2,
                     unsigned short* __restrict__ wbf, float* __restrict__ bias384) {
  const int bid = blockIdx.x, tid = threadIdx.x;
  if (bid < 544) {                     // plain fp32->bf16 converts
    const int cum[8]  = {0, 65536, 131072, 163840, 196608, 262144, 294912, 557056};
    const int dsto[7] = {OFF_KAS, OFF_KAS + 65536, OFF_KAU, OFF_KAU + 32768,
                         OFF_KBS, OFF_KBS + 65536, OFF_W1};
    const int g4 = (bid * 256 + tid) * 4;
    if (g4 < 557056) {
      int seg = 0;
      #pragma unroll
      for (int i = 1; i < 7; ++i) seg += (g4 >= cum[i]) ? 1 : 0;
      const float4 f = *(const float4*)(cp.s[seg] + (g4 - cum[seg]));
      uint2 h;
      h.x = cvtpk(f.x, f.y);
      h.y = cvtpk(f.z, f.w);
      *(uint2*)(wbf + dsto[seg] + (g4 - cum[seg])) = h;
    }
  } else if (bid < 544 + 192) {        // fused [WB;WD] = [B2;D2] @ W2
    const int fb  = bid - 544;
    const int rb8 = (fb >> 2) * 8;     // never straddles 256
    const int k   = (fb & 3) * 256 + tid;
    float acc[8] = {};
    for (int j = 0; j < 256; ++j) {
      const float w2v = W2[(size_t)j * 1024 + k];
      #pragma unroll
      for (int r = 0; r < 8; ++r) {
        const int row = rb8 + r;
        const float sv = (row < 256) ? B2[row * 256 + j] : D2[(row - 256) * 256 + j];
        acc[r] += sv * w2v;
      }
    }
    #pragma unroll
    for (int r = 0; r < 8; ++r)
      wbf[OFF_KBH + (size_t)(rb8 + r) * 1024 + k] = f2bf(acc[r]);
  } else {                              // bias384 = [B2;D2] @ b2
    const int r = (bid - 736) * 256 + tid;
    if (r < 384) {
      const float* S = (r < 256) ? (B2 + r * 256) : (D2 + (r - 256) * 256);
      float a = 0.f;
      for (int j = 0; j < 256; ++j) a += S[j] * b2[j];
      bias384[r] = a;
    }
  }
}

// ============== KA: [ns1 | v] = [s1|u] @ Wcatᵀ, 1-barrier panel ==============
#define XLD 392   // [64][392] bf16 = 50176 B; 392*2 % 16 == 0; dword stride 196 ≡ 4 mod 32
__global__ __launch_bounds__(512, 4) void ka(
    const float* __restrict__ s1, const float* __restrict__ u,
    const unsigned short* __restrict__ wbf,
    float* __restrict__ ns1, unsigned short* __restrict__ vout)
{
  __shared__ unsigned short xb[64 * XLD];
  const int t = threadIdx.x, wc = t >> 6, lid = t & 63;
  const int lr = lid & 15, lg = lid >> 4;
  const int row0 = blockIdx.x * 64;

  // stage s1 [64][256]: 4096 quads, 8/thread
  #pragma unroll
  for (int i = 0; i < 8; ++i) {
    const int q = t + i * 512;
    const int r = q >> 6, c4 = (q & 63) * 4;
    const float4 f = *(const float4*)(s1 + (size_t)(row0 + r) * 256 + c4);
    uint2 h; h.x = cvtpk(f.x, f.y); h.y = cvtpk(f.z, f.w);
    *(uint2*)(xb + r * XLD + c4) = h;
  }
  // stage u [64][128]: 2048 quads, 4/thread -> cols 256..383
  #pragma unroll
  for (int i = 0; i < 4; ++i) {
    const int q = t + i * 512;
    const int r = q >> 5, c4 = (q & 31) * 4;
    const float4 f = *(const float4*)(u + (size_t)(row0 + r) * 128 + c4);
    uint2 h; h.x = cvtpk(f.x, f.y); h.y = cvtpk(f.z, f.w);
    *(uint2*)(xb + r * XLD + 256 + c4) = h;
  }
  __syncthreads();

  f32x4 acc[4][4] = {};
  #pragma unroll
  for (int ks = 0; ks < 12; ++ks) {
    const int kx = ks * 32;
    bf16x8 a[4];
    #pragma unroll
    for (int m = 0; m < 4; ++m)
      a[m] = *(const bf16x8*)(xb + (m * 16 + lr) * XLD + kx + lg * 8);
    const unsigned short* W = (ks < 8) ? (wbf + OFF_KAS) : (wbf + OFF_KAU);
    const int wld = (ks < 8) ? 256 : 128;
    const int kw  = (ks < 8) ? kx : kx - 256;
    #pragma unroll
    for (int n = 0; n < 4; ++n) {
      bf16x8 b = *(const bf16x8*)(W + (size_t)(wc * 64 + n * 16 + lr) * wld + kw + lg * 8);
      #pragma unroll
      for (int m = 0; m < 4; ++m) MFMA16(acc[m][n], a[m], b);
    }
  }
  if (wc < 4) {          // ns1 cols wc*64..
    #pragma unroll
    for (int m = 0; m < 4; ++m)
      #pragma unroll
      for (int n = 0; n < 4; ++n)
        #pragma unroll
        for (int i = 0; i < 4; ++i)
          ns1[(size_t)(row0 + m * 16 + lg * 4 + i) * 256 + wc * 64 + n * 16 + lr] = acc[m][n][i];
  } else {               // v bf16 cols (wc-4)*64..
    #pragma unroll
    for (int m = 0; m < 4; ++m)
      #pragma unroll
      for (int n = 0; n < 4; ++n)
        #pragma unroll
        for (int i = 0; i < 4; ++i)
          vout[(size_t)(row0 + m * 16 + lg * 4 + i) * 256 + (wc - 4) * 64 + n * 16 + lr] = f2bf(acc[m][n][i]);
  }
}

// ===== KB: [ns2|y] = s2@[A2;C2]ᵀ + tanh(v@W1ᵀ+b1)@[WB;WD]ᵀ + bias =====
// hidden chunks of 256, n=2 production (ratio 0.5), n=3 consumption
#define VLD 264
#define CLD 72
__global__ __launch_bounds__(512, 4) void kb(
    const float* __restrict__ s2, const unsigned short* __restrict__ vsrc,
    const unsigned short* __restrict__ wbf,
    const float* __restrict__ b1, const float* __restrict__ bias384,
    float* __restrict__ out2, float* __restrict__ outy)
{
  __shared__ unsigned short vb[64 * VLD];   // 33792 B
  __shared__ unsigned short hb[64 * VLD];   // 33792 B; s2-phase aliases cb0/cb1 here
  unsigned short* cb0 = hb;
  unsigned short* cb1 = hb + 64 * CLD;

  const int t = threadIdx.x, wc = t >> 6, lid = t & 63;
  const int lr = lid & 15, lg = lid >> 4;
  const int row0 = blockIdx.x * 64;

  // stage v -> vb (bf16 copy, padded stride)
  #pragma unroll
  for (int g = 0; g < 4; ++g) {
    const int gi = t + g * 512;
    const int row = gi >> 5, c8 = (gi & 31) * 8;
    *(uint4*)(vb + row * VLD + c8) =
        *(const uint4*)(vsrc + (size_t)(row0 + row) * 256 + c8);
  }

  float4 st0, st1;
  auto stageLoad = [&](int c0) {
    const int cg = t & 15, r0 = t >> 4;
    st0 = *(const float4*)(s2 + (size_t)(row0 + r0) * 256 + c0 + cg * 4);
    st1 = *(const float4*)(s2 + (size_t)(row0 + r0 + 32) * 256 + c0 + cg * 4);
  };
  auto stageWrite = [&](unsigned short* dst) {
    const int cg = t & 15, r0 = t >> 4;
    uint2 h0, h1;
    h0.x = cvtpk(st0.x, st0.y); h0.y = cvtpk(st0.z, st0.w);
    h1.x = cvtpk(st1.x, st1.y); h1.y = cvtpk(st1.z, st1.w);
    *(uint2*)(dst + r0 * CLD + cg * 4) = h0;
    *(uint2*)(dst + (r0 + 32) * CLD + cg * 4) = h1;
  };

  f32x4 acc[4][3] = {};
  // ---- s2 part: acc += s2 @ [A2;C2]ᵀ ----
  stageLoad(0);
  stageWrite(cb0);
  __syncthreads();    // also covers vb staging
  for (int c = 0; c < 4; ++c) {
    if (c < 3) stageLoad((c + 1) * 64);
    const unsigned short* cbuf = (c & 1) ? cb1 : cb0;
    #pragma unroll
    for (int k2 = 0; k2 < 2; ++k2) {
      bf16x8 a[4];
      #pragma unroll
      for (int m = 0; m < 4; ++m)
        a[m] = *(const bf16x8*)(cbuf + (m * 16 + lr) * CLD + k2 * 32 + lg * 8);
      #pragma unroll
      for (int n = 0; n < 3; ++n) {
        bf16x8 b = *(const bf16x8*)(wbf + OFF_KBS +
            (size_t)(wc * 48 + n * 16 + lr) * 256 + c * 64 + k2 * 32 + lg * 8);
        #pragma unroll
        for (int m = 0; m < 4; ++m) MFMA16(acc[m][n], a[m], b);
      }
    }
    if (c < 3) stageWrite((c & 1) ? cb0 : cb1);
    __syncthreads();
  }

  // ---- h part: 4 chunks of 256 hidden ----
  for (int hc = 0; hc < 4; ++hc) {
    f32x4 hac[4][2] = {};
    #pragma unroll
    for (int k = 0; k < 8; ++k) {
      bf16x8 a[4];
      #pragma unroll
      for (int m = 0; m < 4; ++m)
        a[m] = *(const bf16x8*)(vb + (m * 16 + lr) * VLD + k * 32 + lg * 8);
      #pragma unroll
      for (int n = 0; n < 2; ++n) {
        bf16x8 bw = *(const bf16x8*)(wbf + OFF_W1 +
            (size_t)(hc * 256 + wc * 32 + n * 16 + lr) * 256 + k * 32 + lg * 8);
        #pragma unroll
        for (int m = 0; m < 4; ++m) MFMA16(hac[m][n], a[m], bw);
      }
    }
    #pragma unroll
    for (int n = 0; n < 2; ++n) {
      const float b1v = b1[hc * 256 + wc * 32 + n * 16 + lr];
      #pragma unroll
      for (int m = 0; m < 4; ++m)
        #pragma unroll
        for (int i = 0; i < 4; ++i)
          hb[(m * 16 + lg * 4 + i) * VLD + wc * 32 + n * 16 + lr] =
              f2bf(fast_tanh(hac[m][n][i] + b1v));
    }
    __syncthreads();   // hb chunk visible
    #pragma unroll
    for (int kk = 0; kk < 8; ++kk) {
      bf16x8 a[4];
      #pragma unroll
      for (int m = 0; m < 4; ++m)
        a[m] = *(const bf16x8*)(hb + (m * 16 + lr) * VLD + kk * 32 + lg * 8);
      #pragma unroll
      for (int n = 0; n < 3; ++n) {
        bf16x8 b = *(const bf16x8*)(wbf + OFF_KBH +
            (size_t)(wc * 48 + n * 16 + lr) * 1024 + hc * 256 + kk * 32 + lg * 8);
        #pragma unroll
        for (int m = 0; m < 4; ++m) MFMA16(acc[m][n], a[m], b);
      }
    }
    __syncthreads();   // hb reads done before next chunk's writes
  }

  // ---- epilogue: + bias, split ns2 / y ----
  #pragma unroll
  for (int n = 0; n < 3; ++n) {
    const int col = wc * 48 + n * 16 + lr;
    const float bv = bias384[col];
    #pragma unroll
    for (int m = 0; m < 4; ++m)
      #pragma unroll
      for (int i = 0; i < 4; ++i) {
        const size_t row = row0 + m * 16 + lg * 4 + i;
        const float val = acc[m][n][i] + bv;
        if (col < 256) out2[row * 256 + col] = val;
        else           outy[row * 128 + col - 256] = val;
      }
  }
}

extern "C" void kernel_launch(void* const* d_in, const int* in_sizes, int n_in,
                              void* d_out, int out_size, void* d_ws, size_t ws_size,
                              hipStream_t stream) {
  const float* s1 = (const float*)d_in[0];
  const float* s2 = (const float*)d_in[1];
  const float* u  = (const float*)d_in[2];
  CvtPtrs cp;
  cp.s[0] = (const float*)d_in[3];   // A1
  cp.s[1] = (const float*)d_in[5];   // C1
  cp.s[2] = (const float*)d_in[4];   // B1
  cp.s[3] = (const float*)d_in[6];   // D1
  cp.s[4] = (const float*)d_in[7];   // A2
  cp.s[5] = (const float*)d_in[9];   // C2
  cp.s[6] = (const float*)d_in[11];  // W1
  const float* B2 = (const float*)d_in[8];
  const float* D2 = (const float*)d_in[10];
  const float* W2 = (const float*)d_in[13];
  const float* b1 = (const float*)d_in[12];
  const float* b2 = (const float*)d_in[14];

  unsigned short* wbf = (unsigned short*)d_ws;
  float* bias384 = (float*)((char*)d_ws + OFF_BIAS_BYTES);
  float* out = (float*)d_out;
  float* out2 = out + (size_t)NB * 256;
  float* outy = out + (size_t)NB * 512;
  // v (bf16, 32 MB) lives in the y-region (64 MB) until KB overwrites y
  unsigned short* vtmp = (unsigned short*)outy;

  prep<<<dim3(738), dim3(256), 0, stream>>>(cp, B2, D2, W2, b2, wbf, bias384);
  ka<<<dim3(NB / 64), dim3(512), 0, stream>>>(s1, u, wbf, out, vtmp);
  kb<<<dim3(NB / 64), dim3(512), 0, stream>>>(s2, vtmp, wbf, b1, bias384, out2, outy);
}

// Round 8
// 325.386 us; speedup vs baseline: 1.4281x; 1.0553x over previous
//
#include <hip/hip_runtime.h>

#define NB 65536

typedef __attribute__((ext_vector_type(8))) short bf16x8;
typedef __attribute__((ext_vector_type(4))) float f32x4;

__device__ __forceinline__ unsigned cvtpk(float lo, float hi) {
  unsigned r;
  asm("v_cvt_pk_bf16_f32 %0, %1, %2" : "=v"(r) : "v"(lo), "v"(hi));
  return r;
}
__device__ __forceinline__ unsigned short f2bf(float f) {
  union { float f; unsigned u; } v; v.f = f;
  return (unsigned short)((v.u + 0x7FFFu + ((v.u >> 16) & 1u)) >> 16);
}
__device__ __forceinline__ float fast_tanh(float x) {
  float e = __builtin_amdgcn_exp2f(__builtin_fabsf(x) * -2.885390081777927f);
  float t = (1.0f - e) * __builtin_amdgcn_rcpf(1.0f + e);
  return __builtin_copysignf(t, x);
}
// async global->LDS, 16B per lane. dest = wave-uniform base + lane*16;
// passing base + t*8 elems gives lane-linear fill (lane0 holds the base).
__device__ __forceinline__ void gld16(const unsigned short* g, unsigned short* l) {
  __builtin_amdgcn_global_load_lds(
      (const __attribute__((address_space(1))) void*)g,
      (__attribute__((address_space(3))) void*)l, 16, 0, 0);
}

#define MFMA16(acc, a, b) \
  acc = __builtin_amdgcn_mfma_f32_16x16x32_bf16(a, b, acc, 0, 0, 0)

// ws layout (bf16 element offsets) — all weights k-slice packed [NS][N][32]
#define OFF_W1P  0        // [2 nh][8 ks][512][32]
#define OFF_KAVP 262144   // [12 ks][256][32]  rows=[C1|D1] k-concat
#define OFF_KANP 360448   // [12 ks][256][32]  rows=[A1|B1]
#define OFF_KBSP 458752   // [8 ks][384][32]   rows=[A2;C2]
#define OFF_KBHP 557056   // [32 ks][384][32]  rows=[B2@W2 ; D2@W2] (fused)
#define WS_END   950272
#define OFF_BIAS_BYTES ((size_t)WS_END * 2)

// ===================== prep: pack weights + fuse [B2;D2]@W2 =====================
struct PP {
  const float *A1, *B1, *C1, *D1, *A2, *B2, *C2, *D2, *W1, *W2, *b2;
};

__global__ void prep(PP p, unsigned short* __restrict__ wbf, float* __restrict__ bias384) {
  const int bid = blockIdx.x, t = threadIdx.x;
  if (bid < 272) {                       // pack W1P/KAVP/KANP/KBSP (8 elems/thread)
    const int e8 = (bid * 256 + t) * 8;  // 272*256*8 == 557056 exactly
    const float* src;
    if (e8 < 262144) {                   // W1P [2][8][512][32]
      const int nh = e8 / 131072, r = e8 % 131072;
      const int ks = r / 16384, n = (r / 32) % 512, kk = r % 32;
      src = p.W1 + (size_t)(nh * 512 + n) * 256 + ks * 32 + kk;
    } else if (e8 < 360448) {            // KAVP [12][256][32]
      const int q = e8 - 262144;
      const int ks = q / 8192, n = (q / 32) % 256, kk = q % 32;
      src = (ks < 8) ? p.C1 + (size_t)n * 256 + ks * 32 + kk
                     : p.D1 + (size_t)n * 128 + (ks - 8) * 32 + kk;
    } else if (e8 < 458752) {            // KANP [12][256][32]
      const int q = e8 - 360448;
      const int ks = q / 8192, n = (q / 32) % 256, kk = q % 32;
      src = (ks < 8) ? p.A1 + (size_t)n * 256 + ks * 32 + kk
                     : p.B1 + (size_t)n * 128 + (ks - 8) * 32 + kk;
    } else {                             // KBSP [8][384][32]
      const int q = e8 - 458752;
      const int ks = q / 12288, n = (q / 32) % 384, kk = q % 32;
      src = (n < 256) ? p.A2 + (size_t)n * 256 + ks * 32 + kk
                      : p.C2 + (size_t)(n - 256) * 256 + ks * 32 + kk;
    }
    const float4 f0 = *(const float4*)src, f1 = *(const float4*)(src + 4);
    uint4 h;
    h.x = cvtpk(f0.x, f0.y); h.y = cvtpk(f0.z, f0.w);
    h.z = cvtpk(f1.x, f1.y); h.w = cvtpk(f1.z, f1.w);
    *(uint4*)(wbf + e8) = h;
  } else if (bid < 272 + 192) {          // KBHP = [B2;D2] @ W2, packed
    const int fb = bid - 272;
    const int rb8 = (fb >> 2) * 8;       // row block of 8 (never straddles 256)
    const int k = (fb & 3) * 256 + t;
    float acc[8] = {};
    for (int j = 0; j < 256; ++j) {
      const float w2v = p.W2[(size_t)j * 1024 + k];
      #pragma unroll
      for (int r = 0; r < 8; ++r) {
        const int row = rb8 + r;
        const float sv = (row < 256) ? p.B2[row * 256 + j] : p.D2[(row - 256) * 256 + j];
        acc[r] += sv * w2v;
      }
    }
    #pragma unroll
    for (int r = 0; r < 8; ++r)
      wbf[OFF_KBHP + (size_t)(k >> 5) * 12288 + (rb8 + r) * 32 + (k & 31)] = f2bf(acc[r]);
  } else {                               // bias384 = [B2;D2] @ b2
    const int r = (bid - 464) * 256 + t;
    if (r < 384) {
      const float* S = (r < 256) ? (p.B2 + r * 256) : (p.D2 + (r - 256) * 256);
      float a = 0.f;
      for (int j = 0; j < 256; ++j) a += S[j] * p.b2[j];
      bias384[r] = a;
    }
  }
}

// ======= k256: C[128,256] = [s1|u] @ Wpackᵀ (kav: bf16 v; kan: fp32 ns1) =======
__global__ __launch_bounds__(512, 4) void k256(
    const float* __restrict__ s1, const float* __restrict__ u,
    const unsigned short* __restrict__ wbf, int boff,
    float* __restrict__ outf, unsigned short* __restrict__ outb)
{
  __shared__ unsigned short Ab[2][4096];   //  8KB x2  [128][32]
  __shared__ unsigned short Bb[2][8192];   // 16KB x2  [256][32]
  const int t = threadIdx.x, wc = t >> 6, lid = t & 63;
  const int lr = lid & 15, lg = lid >> 4;
  const int wm = wc >> 2, wn = wc & 3;
  const int row0 = blockIdx.x * 128;

  float4 f0, f1;
  auto aload = [&](int ks) {
    const float* src; int ld, c0;
    if (ks < 8) { src = s1; ld = 256; c0 = ks * 32; }
    else        { src = u;  ld = 128; c0 = ks * 32 - 256; }
    const float* q = src + (size_t)(row0 + (t >> 2)) * ld + c0 + (t & 3) * 8;
    f0 = *(const float4*)q; f1 = *(const float4*)(q + 4);
  };
  auto awrite = [&](int buf) {
    uint4 h;
    h.x = cvtpk(f0.x, f0.y); h.y = cvtpk(f0.z, f0.w);
    h.z = cvtpk(f1.x, f1.y); h.w = cvtpk(f1.z, f1.w);
    *(uint4*)(&Ab[buf][(t >> 2) * 32 + (t & 3) * 8]) = h;
  };
  auto bstage = [&](int ks, int buf) {
    const unsigned short* src = wbf + boff + ks * 8192 + t * 8;
    gld16(src, &Bb[buf][t * 8]);
    gld16(src + 4096, &Bb[buf][4096 + t * 8]);
  };

  f32x4 acc[4][4] = {};
  aload(0); awrite(0); bstage(0, 0);
  __syncthreads();
  for (int ks = 0; ks < 12; ++ks) {
    const int cur = ks & 1;
    if (ks < 11) { aload(ks + 1); bstage(ks + 1, cur ^ 1); }
    bf16x8 a[4], b[4];
    #pragma unroll
    for (int m = 0; m < 4; ++m)
      a[m] = *(const bf16x8*)&Ab[cur][(wm * 64 + m * 16 + lr) * 32 + lg * 8];
    #pragma unroll
    for (int n = 0; n < 4; ++n)
      b[n] = *(const bf16x8*)&Bb[cur][(wn * 64 + n * 16 + lr) * 32 + lg * 8];
    #pragma unroll
    for (int n = 0; n < 4; ++n)
      #pragma unroll
      for (int m = 0; m < 4; ++m) MFMA16(acc[m][n], a[m], b[n]);
    if (ks < 11) awrite(cur ^ 1);
    __syncthreads();
  }
  if (outf) {
    #pragma unroll
    for (int m = 0; m < 4; ++m)
      #pragma unroll
      for (int n = 0; n < 4; ++n)
        #pragma unroll
        for (int i = 0; i < 4; ++i)
          outf[(size_t)(row0 + wm * 64 + m * 16 + lg * 4 + i) * 256 + wn * 64 + n * 16 + lr] = acc[m][n][i];
  } else {
    #pragma unroll
    for (int m = 0; m < 4; ++m)
      #pragma unroll
      for (int n = 0; n < 4; ++n)
        #pragma unroll
        for (int i = 0; i < 4; ++i)
          outb[(size_t)(row0 + wm * 64 + m * 16 + lg * 4 + i) * 256 + wn * 64 + n * 16 + lr] = f2bf(acc[m][n][i]);
  }
}

// ========== kbh: h[:,nh*512..] = tanh(v @ W1ᵀ + b1), bf16 to h0/h1 ==========
__global__ __launch_bounds__(512, 4) void kbh(
    const unsigned short* __restrict__ vsrc, const unsigned short* __restrict__ wbf,
    const float* __restrict__ b1,
    unsigned short* __restrict__ h0, unsigned short* __restrict__ h1)
{
  __shared__ unsigned short Ab[2][2048];    //  4KB x2 [64][32]
  __shared__ unsigned short Bb[2][16384];   // 32KB x2 [512][32]
  const int t = threadIdx.x, wc = t >> 6, lid = t & 63;
  const int lr = lid & 15, lg = lid >> 4;
  const int nh = blockIdx.x & 1;
  const int row0 = (blockIdx.x >> 1) * 64;

  auto astage = [&](int ks, int buf) {
    if (t < 256) {
      const unsigned short* src = vsrc + (size_t)(row0 + (t >> 2)) * 256 + ks * 32 + (t & 3) * 8;
      gld16(src, &Ab[buf][t * 8]);
    }
  };
  auto bstage = [&](int ks, int buf) {
    const unsigned short* src = wbf + OFF_W1P + nh * 131072 + ks * 16384 + t * 8;
    #pragma unroll
    for (int i = 0; i < 4; ++i)
      gld16(src + i * 4096, &Bb[buf][i * 4096 + t * 8]);
  };

  f32x4 acc[4][4] = {};
  astage(0, 0); bstage(0, 0);
  __syncthreads();
  for (int ks = 0; ks < 8; ++ks) {
    const int cur = ks & 1;
    if (ks < 7) { astage(ks + 1, cur ^ 1); bstage(ks + 1, cur ^ 1); }
    bf16x8 a[4], b[4];
    #pragma unroll
    for (int m = 0; m < 4; ++m)
      a[m] = *(const bf16x8*)&Ab[cur][(m * 16 + lr) * 32 + lg * 8];
    #pragma unroll
    for (int n = 0; n < 4; ++n)
      b[n] = *(const bf16x8*)&Bb[cur][(wc * 64 + n * 16 + lr) * 32 + lg * 8];
    #pragma unroll
    for (int n = 0; n < 4; ++n)
      #pragma unroll
      for (int m = 0; m < 4; ++m) MFMA16(acc[m][n], a[m], b[n]);
    __syncthreads();
  }
  // tanh + bias -> LDS pack [64][512] (reuse Bb) -> coalesced copy out
  unsigned short* hp = &Bb[0][0];
  #pragma unroll
  for (int n = 0; n < 4; ++n) {
    const int colc = wc * 64 + n * 16 + lr;
    const float b1v = b1[nh * 512 + colc];
    #pragma unroll
    for (int m = 0; m < 4; ++m)
      #pragma unroll
      for (int i = 0; i < 4; ++i)
        hp[(m * 16 + lg * 4 + i) * 512 + colc] = f2bf(fast_tanh(acc[m][n][i] + b1v));
  }
  __syncthreads();
  unsigned short* hdst = nh ? h1 : h0;
  const int row = t >> 3, cc = (t & 7) * 64;
  #pragma unroll
  for (int i = 0; i < 8; ++i)
    *(uint4*)(hdst + (size_t)(row0 + row) * 512 + cc + i * 8) =
        *(const uint4*)(hp + row * 512 + cc + i * 8);
}

// == kbc: [ns2|y] = s2@KBSᵀ + h@KBHᵀ + bias; writes IN-PLACE over h1-rows/v-rows ==
__global__ __launch_bounds__(512, 4) void kbc(
    const float* __restrict__ s2,
    const unsigned short* __restrict__ h0, const unsigned short* __restrict__ h1,
    const unsigned short* __restrict__ wbf, const float* __restrict__ bias384,
    float* __restrict__ ns2, float* __restrict__ y)
{
  __shared__ unsigned short Ab[2][2048];    //  4KB x2 [64][32]
  __shared__ unsigned short Bb[2][12288];   // 24KB x2 [384][32]
  const int t = threadIdx.x, wc = t >> 6, lid = t & 63;
  const int lr = lid & 15, lg = lid >> 4;
  const int row0 = blockIdx.x * 64;

  float4 f0, f1;
  auto aload = [&](int ks) {       // s2 fp32 (ks<8), threads 0..255
    if (t < 256) {
      const float* q = s2 + (size_t)(row0 + (t >> 2)) * 256 + ks * 32 + (t & 3) * 8;
      f0 = *(const float4*)q; f1 = *(const float4*)(q + 4);
    }
  };
  auto awrite = [&](int buf) {
    if (t < 256) {
      uint4 h;
      h.x = cvtpk(f0.x, f0.y); h.y = cvtpk(f0.z, f0.w);
      h.z = cvtpk(f1.x, f1.y); h.w = cvtpk(f1.z, f1.w);
      *(uint4*)(&Ab[buf][(t >> 2) * 32 + (t & 3) * 8]) = h;
    }
  };
  auto astage_h = [&](int ks, int buf) {   // h bf16 (ks>=8), threads 0..255
    if (t < 256) {
      const int hk = (ks - 8) * 32;
      const unsigned short* reg = (hk < 512) ? h0 : h1;
      const unsigned short* src = reg + (size_t)(row0 + (t >> 2)) * 512 + (hk & 511) + (t & 3) * 8;
      gld16(src, &Ab[buf][t * 8]);
    }
  };
  auto bstage = [&](int ks, int buf) {
    const size_t boff = (ks < 8) ? (OFF_KBSP + (size_t)ks * 12288)
                                 : (OFF_KBHP + (size_t)(ks - 8) * 12288);
    const unsigned short* src = wbf + boff + t * 8;
    #pragma unroll
    for (int i = 0; i < 3; ++i)
      gld16(src + i * 4096, &Bb[buf][i * 4096 + t * 8]);
  };

  f32x4 acc[4][3] = {};
  aload(0); awrite(0); bstage(0, 0);
  __syncthreads();
  for (int ks = 0; ks < 40; ++ks) {
    const int cur = ks & 1;
    if (ks < 39) {
      if (ks + 1 < 8) aload(ks + 1);
      else            astage_h(ks + 1, cur ^ 1);
      bstage(ks + 1, cur ^ 1);
    }
    bf16x8 a[4], b[3];
    #pragma unroll
    for (int m = 0; m < 4; ++m)
      a[m] = *(const bf16x8*)&Ab[cur][(m * 16 + lr) * 32 + lg * 8];
    #pragma unroll
    for (int n = 0; n < 3; ++n)
      b[n] = *(const bf16x8*)&Bb[cur][(wc * 48 + n * 16 + lr) * 32 + lg * 8];
    #pragma unroll
    for (int n = 0; n < 3; ++n)
      #pragma unroll
      for (int m = 0; m < 4; ++m) MFMA16(acc[m][n], a[m], b[n]);
    if (ks < 39 && ks + 1 < 8) awrite(cur ^ 1);
    __syncthreads();
  }
  #pragma unroll
  for (int n = 0; n < 3; ++n) {
    const int col = wc * 48 + n * 16 + lr;
    const float bv = bias384[col];
    #pragma unroll
    for (int m = 0; m < 4; ++m)
      #pragma unroll
      for (int i = 0; i < 4; ++i) {
        const size_t row = row0 + m * 16 + lg * 4 + i;
        const float val = acc[m][n][i] + bv;
        if (col < 256) ns2[row * 256 + col] = val;
        else           y[row * 128 + col - 256] = val;
      }
  }
}

extern "C" void kernel_launch(void* const* d_in, const int* in_sizes, int n_in,
                              void* d_out, int out_size, void* d_ws, size_t ws_size,
                              hipStream_t stream) {
  const float* s1 = (const float*)d_in[0];
  const float* s2 = (const float*)d_in[1];
  const float* u  = (const float*)d_in[2];
  PP p;
  p.A1 = (const float*)d_in[3];
  p.B1 = (const float*)d_in[4];
  p.C1 = (const float*)d_in[5];
  p.D1 = (const float*)d_in[6];
  p.A2 = (const float*)d_in[7];
  p.B2 = (const float*)d_in[8];
  p.C2 = (const float*)d_in[9];
  p.D2 = (const float*)d_in[10];
  p.W1 = (const float*)d_in[11];
  p.W2 = (const float*)d_in[13];
  p.b2 = (const float*)d_in[14];
  const float* b1 = (const float*)d_in[12];

  unsigned short* wbf = (unsigned short*)d_ws;
  float* bias384 = (float*)((char*)d_ws + OFF_BIAS_BYTES);
  float* out = (float*)d_out;
  float* out2 = out + (size_t)NB * 256;     // ns2 region (64MB)
  float* outy = out + (size_t)NB * 512;     // y region (32MB)
  // region reuse: v lives in y-region; h = [out2-region | ns1-region]
  unsigned short* vtmp = (unsigned short*)outy;              // [65536][256] bf16 = 32MB
  unsigned short* h0   = (unsigned short*)out2;              // h cols 0..511   (64MB)
  unsigned short* h1   = (unsigned short*)out;               // h cols 512..1023 (64MB)

  prep<<<dim3(466), dim3(256), 0, stream>>>(p, wbf, bias384);
  // kav: v = s1@C1ᵀ + u@D1ᵀ  -> vtmp (bf16)
  k256<<<dim3(NB / 128), dim3(512), 0, stream>>>(s1, u, wbf, OFF_KAVP, nullptr, vtmp);
  // kbh: h = tanh(v@W1ᵀ + b1) -> h0|h1 (bf16)
  kbh<<<dim3((NB / 64) * 2), dim3(512), 0, stream>>>(vtmp, wbf, b1, h0, h1);
  // kbc: ns2,y = s2@[A2;C2]ᵀ + h@[WB;WD]ᵀ + bias  (in-place rows over h0 / vtmp)
  kbc<<<dim3(NB / 64), dim3(512), 0, stream>>>(s2, h0, h1, wbf, bias384, out2, outy);
  // kan: ns1 = s1@A1ᵀ + u@B1ᵀ -> out (overwrites h1, already consumed)
  k256<<<dim3(NB / 128), dim3(512), 0, stream>>>(s1, u, wbf, OFF_KANP, out, nullptr);
}